// Round 5
// baseline (852.016 us; speedup 1.0000x reference)
//
#include <hip/hip_runtime.h>

typedef unsigned short u16;
typedef unsigned int u32;

typedef __attribute__((ext_vector_type(8))) short short8;
typedef __attribute__((ext_vector_type(4))) float float4v;

__device__ __forceinline__ float bf2f(u16 u) { return __uint_as_float(((u32)u) << 16); }
__device__ __forceinline__ u16 f2bf(float f) {
    u32 x = __float_as_uint(f);
    return (u16)((x + 0x7fffu + ((x >> 16) & 1u)) >> 16);
}
__device__ __forceinline__ float sigmoidf_(float x) { return 1.0f / (1.0f + expf(-x)); }

#define B_ 128
#define T_ 20
#define VISN 196
#define VISD 512
#define EMB 256
#define HID 512
#define VOC 10000
#define VOCP 10112   /* padded to 79*128 */
#define NBLK 64      /* recurrence grid */

// ---------------------------------------------------------------------------
// fused weight conversion f32 -> bf16 (+ zero-pad Wo/bo to VOCP, zero flags)
// ---------------------------------------------------------------------------
__global__ __launch_bounds__(256) void conv_all(
    const float* __restrict__ Wih, const float* __restrict__ Whh,
    const float* __restrict__ Wo,  const float* __restrict__ Winh,
    const float* __restrict__ Winc, const float* __restrict__ bih,
    const float* __restrict__ bhh, const float* __restrict__ bo,
    u16* __restrict__ cWih, u16* __restrict__ cWhh, u16* __restrict__ cWo,
    u16* __restrict__ cWinit, u16* __restrict__ cbih, u16* __restrict__ cbhh,
    u16* __restrict__ cbo, int* __restrict__ flags) {
    const int e0 = 1572864, e1 = 2621440, e2 = 7798784, e3 = 8060928,
              e4 = 8323072, e5 = 8325120, e6 = 8327168, e7 = 8337280;
    int gid = blockIdx.x * 256 + threadIdx.x;
    if (gid < 2048) flags[gid] = 0;   // barrier flags (64 x 128B-padded)
    if (gid >= e7) return;
    if (gid < e0) { cWih[gid] = f2bf(Wih[gid]); }
    else if (gid < e1) { int l = gid - e0; cWhh[l] = f2bf(Whh[l]); }
    else if (gid < e2) {
        int l = gid - e1; int row = l >> 9, col = l & 511;
        cWo[l] = (row < VOC) ? f2bf(Wo[(size_t)row * 512 + col]) : (u16)0;
    }
    else if (gid < e3) { int l = gid - e2; cWinit[l] = f2bf(Winh[l]); }
    else if (gid < e4) { int l = gid - e3; cWinit[262144 + l] = f2bf(Winc[l]); }
    else if (gid < e5) { int l = gid - e4; cbih[l] = f2bf(bih[l]); }
    else if (gid < e6) { int l = gid - e5; cbhh[l] = f2bf(bhh[l]); }
    else { int l = gid - e6; cbo[l] = (l < VOC) ? f2bf(bo[l]) : (u16)0; }
}

// ---------------------------------------------------------------------------
// fused prep: alpha = softmax_n(features[b,n,:]·Wv) (h-term is constant over
// n -> softmax-invariant -> dropped); fbar = mean_n feat; ctx = sum alpha*feat.
// One block per b; phase-2 re-reads features[b] (L2-hot from phase 1).
// ---------------------------------------------------------------------------
__global__ __launch_bounds__(256) void prep2(const float* __restrict__ feat,
                                             const float* __restrict__ Wv,
                                             u16* __restrict__ fbar_bf,
                                             u16* __restrict__ ctx_bf) {
    __shared__ float wv[512];
    __shared__ float att[VISN];
    __shared__ float red[256];
    int b = blockIdx.x, tid = threadIdx.x;
    wv[tid] = Wv[tid];
    wv[tid + 256] = Wv[tid + 256];
    __syncthreads();
    int w = tid >> 6, lane = tid & 63;
    for (int n = w; n < VISN; n += 4) {
        const float4* fp = (const float4*)(feat + ((size_t)b * VISN + n) * VISD) + lane * 2;
        float4 a = fp[0], c = fp[1];
        const float* wp = wv + lane * 8;
        float s = a.x * wp[0] + a.y * wp[1] + a.z * wp[2] + a.w * wp[3]
                + c.x * wp[4] + c.y * wp[5] + c.z * wp[6] + c.w * wp[7];
        #pragma unroll
        for (int off = 32; off; off >>= 1) s += __shfl_down(s, off);
        if (lane == 0) att[n] = s;
    }
    __syncthreads();
    float m = -1e30f;
    for (int i = tid; i < VISN; i += 256) m = fmaxf(m, att[i]);
    red[tid] = m; __syncthreads();
    for (int s = 128; s; s >>= 1) { if (tid < s) red[tid] = fmaxf(red[tid], red[tid + s]); __syncthreads(); }
    m = red[0]; __syncthreads();
    float sum = 0.f;
    for (int i = tid; i < VISN; i += 256) { float e = expf(att[i] - m); att[i] = e; sum += e; }
    red[tid] = sum; __syncthreads();
    for (int s = 128; s; s >>= 1) { if (tid < s) red[tid] += red[tid + s]; __syncthreads(); }
    float inv = 1.0f / red[0]; __syncthreads();
    for (int i = tid; i < VISN; i += 256) att[i] *= inv;
    __syncthreads();
    #pragma unroll
    for (int half = 0; half < 2; half++) {
        int v = tid + half * 256;
        float accf = 0.f, accc = 0.f;
        const float* fp = feat + (size_t)b * VISN * VISD + v;
        #pragma unroll 4
        for (int n = 0; n < VISN; n++) {
            float f = fp[(size_t)n * VISD];
            accf += f;
            accc += att[n] * f;
        }
        fbar_bf[b * VISD + v] = f2bf(accf / (float)VISN);
        ctx_bf[b * VISD + v] = f2bf(accc);
    }
}

// gather embeddings, time-major r = t*B + b
__global__ void gather_emb(const int* __restrict__ captions, const float* __restrict__ table,
                           u16* __restrict__ Ebf) {
    int r = blockIdx.x;
    int t = r >> 7, b = r & 127;
    int idx = captions[b * T_ + t];
    Ebf[(size_t)r * EMB + threadIdx.x] = f2bf(table[(size_t)idx * EMB + threadIdx.x]);
}

// ---------------------------------------------------------------------------
// bf16 MFMA GEMM, 64x64 tile, BK=32. C = A[M,K]·B[N,K]^T + biases + addA.
// mode 0: bf16 Cbf; mode 1: f32 Cf; mode 2: h0c0 split.
// ---------------------------------------------------------------------------
__global__ __launch_bounds__(256) void gemm_bt(const u16* __restrict__ A, int lda,
                                               const u16* __restrict__ Bm, int ldb,
                                               int M, int N, int K,
                                               const u16* __restrict__ bias0,
                                               const u16* __restrict__ bias1,
                                               const float* __restrict__ addA, int rowmask,
                                               float* __restrict__ Cf,
                                               u16* __restrict__ Cbf, int ldc, int mode) {
    __shared__ u16 As[64 * 32];
    __shared__ u16 Bs[64 * 32];
    int tid = threadIdx.x;
    int n0 = blockIdx.x * 64, m0 = blockIdx.y * 64;
    int w = tid >> 6, lane = tid & 63;
    int wm = (w & 1) * 32, wn = (w >> 1) * 32;
    int mrow = lane & 15, quad = lane >> 4;
    float4v acc[2][2] = {};
    int lr = tid >> 2;
    int lc = (tid & 3) * 8;
    for (int k0 = 0; k0 < K; k0 += 32) {
        *(uint4*)(&As[lr * 32 + lc]) = *(const uint4*)(A + (size_t)(m0 + lr) * lda + k0 + lc);
        *(uint4*)(&Bs[lr * 32 + lc]) = *(const uint4*)(Bm + (size_t)(n0 + lr) * ldb + k0 + lc);
        __syncthreads();
        short8 afrag[2], bfrag[2];
        #pragma unroll
        for (int i = 0; i < 2; i++)
            afrag[i] = *(const short8*)(&As[(wm + i * 16 + mrow) * 32 + quad * 8]);
        #pragma unroll
        for (int j = 0; j < 2; j++)
            bfrag[j] = *(const short8*)(&Bs[(wn + j * 16 + mrow) * 32 + quad * 8]);
        #pragma unroll
        for (int i = 0; i < 2; i++)
            #pragma unroll
            for (int j = 0; j < 2; j++)
                acc[i][j] = __builtin_amdgcn_mfma_f32_16x16x32_bf16(afrag[i], bfrag[j], acc[i][j], 0, 0, 0);
        __syncthreads();
    }
    #pragma unroll
    for (int i = 0; i < 2; i++) {
        #pragma unroll
        for (int j = 0; j < 2; j++) {
            #pragma unroll
            for (int r = 0; r < 4; r++) {
                int grow = m0 + wm + i * 16 + quad * 4 + r;
                int gcol = n0 + wn + j * 16 + mrow;
                float v = acc[i][j][r];
                if (bias0) v += bf2f(bias0[gcol]);
                if (bias1) v += bf2f(bias1[gcol]);
                if (addA) v += addA[(size_t)(grow & rowmask) * ldc + gcol];
                if (mode == 0) {
                    Cbf[(size_t)grow * ldc + gcol] = f2bf(v);
                } else if (mode == 1) {
                    Cf[(size_t)grow * ldc + gcol] = v;
                } else {
                    if (gcol < 512) Cbf[(size_t)grow * 512 + gcol] = f2bf(v);
                    else Cf[(size_t)grow * 512 + gcol - 512] = v;
                }
            }
        }
    }
}

// ---------------------------------------------------------------------------
// persistent fused recurrence. 64 blocks; block j owns gate k-slice [8j,8j+8)
// of all 4 gate groups. W_hh slice LDS-resident; c in registers; h ping-pong
// in global. Per step: depth-2 pipelined h staging (triple-buffered As, one
// sync/chunk), gbase prefetch, flag-array grid barrier (no atomic RMW
// serialization — block j stores flags[j], wave 0 lane l polls flags[l]).
// ---------------------------------------------------------------------------
__global__ __launch_bounds__(256) void recurrence(
    const u16* __restrict__ Whh,      // [2048,512] bf16
    const float* __restrict__ gbase,  // [2560,2048] f32 (row = t*128+b)
    const float* __restrict__ c0,     // [128,512] f32
    u16* __restrict__ h_pp,           // [2][128*512] bf16, buf0 = h0
    u16* __restrict__ h_all,          // [2560,512] bf16
    int* __restrict__ flags) {        // [64] step counters, 128B-padded
    __shared__ u16 Ws[32 * 520];      // 33,280 B (2-way bank alias = free)
    __shared__ u16 AsB[3][128 * 40];  // 30,720 B; Gt aliases this region
    float* Gt = (float*)&AsB[0][0];   // [128,33] f32 = 16,896 B
    int j = blockIdx.x, tid = threadIdx.x;
    // W_hh slice: local col c -> global row (c>>3)*512 + 8j + (c&7)
    for (int idx = tid; idx < 32 * 64; idx += 256) {
        int c = idx >> 6, q = idx & 63;
        int grow = ((c >> 3) << 9) + 8 * j + (c & 7);
        *(uint4*)&Ws[c * 520 + q * 8] = *(const uint4*)&Whh[(size_t)grow * 512 + q * 8];
    }
    float cst[4];
    int pb = tid >> 1, pk = (tid & 1) * 4;
    #pragma unroll
    for (int q = 0; q < 4; q++) cst[q] = c0[pb * 512 + 8 * j + pk + q];
    int arow = tid >> 1, acol = (tid & 1) * 16;   // 32 B of h per thread per chunk
    int w = tid >> 6, lane = tid & 63;
    int mrow = lane & 15, quad = lane >> 4;
    __syncthreads();
    for (int t = 0; t < T_; t++) {
        const u16* hcur = h_pp + (t & 1) * (B_ * HID);
        u16* hnxt = h_pp + ((t + 1) & 1) * (B_ * HID);
        const u16* hrow = hcur + (size_t)arow * 512 + acol;
        // prologue: chunks 0..3 in flight, 0 and 1 staged
        uint4 pa0, pa1, pb0, pb1;
        pa0 = *(const uint4*)(hrow + 0);       pa1 = *(const uint4*)(hrow + 8);
        pb0 = *(const uint4*)(hrow + 32);      pb1 = *(const uint4*)(hrow + 40);
        *(uint4*)&AsB[0][arow * 40 + acol] = pa0;
        *(uint4*)&AsB[0][arow * 40 + acol + 8] = pa1;
        pa0 = *(const uint4*)(hrow + 64);      pa1 = *(const uint4*)(hrow + 72);
        *(uint4*)&AsB[1][arow * 40 + acol] = pb0;
        *(uint4*)&AsB[1][arow * 40 + acol + 8] = pb1;
        pb0 = *(const uint4*)(hrow + 96);      pb1 = *(const uint4*)(hrow + 104);
        // prefetch gbase operands (retire during the k-loop)
        float gb[2][2][4];
        #pragma unroll
        for (int i = 0; i < 2; i++) {
            #pragma unroll
            for (int n2 = 0; n2 < 2; n2++) {
                int lcol = n2 * 16 + mrow;
                int G = ((lcol >> 3) << 9) + 8 * j + (lcol & 7);
                #pragma unroll
                for (int r = 0; r < 4; r++) {
                    int grow = 32 * w + i * 16 + quad * 4 + r;
                    gb[i][n2][r] = gbase[(size_t)(t * B_ + grow) * 2048 + G];
                }
            }
        }
        __syncthreads();
        float4v acc[2][2] = {};
        #pragma unroll
        for (int k = 0; k < 16; k++) {
            const int bcur = k % 3;
            short8 af[2], bfr[2];
            #pragma unroll
            for (int i = 0; i < 2; i++)
                af[i] = *(const short8*)&AsB[bcur][(32 * w + i * 16 + mrow) * 40 + quad * 8];
            #pragma unroll
            for (int n2 = 0; n2 < 2; n2++)
                bfr[n2] = *(const short8*)&Ws[(n2 * 16 + mrow) * 520 + k * 32 + quad * 8];
            #pragma unroll
            for (int i = 0; i < 2; i++)
                #pragma unroll
                for (int n2 = 0; n2 < 2; n2++)
                    acc[i][n2] = __builtin_amdgcn_mfma_f32_16x16x32_bf16(af[i], bfr[n2], acc[i][n2], 0, 0, 0);
            if (k + 2 < 16) {
                const int bw = (k + 2) % 3;
                if (k & 1) {
                    *(uint4*)&AsB[bw][arow * 40 + acol] = pb0;
                    *(uint4*)&AsB[bw][arow * 40 + acol + 8] = pb1;
                } else {
                    *(uint4*)&AsB[bw][arow * 40 + acol] = pa0;
                    *(uint4*)&AsB[bw][arow * 40 + acol + 8] = pa1;
                }
            }
            if (k + 4 < 16) {
                if (k & 1) {
                    pb0 = *(const uint4*)(hrow + (k + 4) * 32);
                    pb1 = *(const uint4*)(hrow + (k + 4) * 32 + 8);
                } else {
                    pa0 = *(const uint4*)(hrow + (k + 4) * 32);
                    pa1 = *(const uint4*)(hrow + (k + 4) * 32 + 8);
                }
            }
            __syncthreads();
        }
        // epilogue: acc + gbase -> Gt (aliases AsB; k-loop reads are done)
        #pragma unroll
        for (int i = 0; i < 2; i++) {
            #pragma unroll
            for (int n2 = 0; n2 < 2; n2++) {
                int lcol = n2 * 16 + mrow;
                #pragma unroll
                for (int r = 0; r < 4; r++) {
                    int grow = 32 * w + i * 16 + quad * 4 + r;
                    Gt[grow * 33 + lcol] = acc[i][n2][r] + gb[i][n2][r];
                }
            }
        }
        __syncthreads();
        // LSTM elementwise on owned slice
        {
            u16 hb[4];
            #pragma unroll
            for (int q = 0; q < 4; q++) {
                int kc = pk + q;
                float ig = sigmoidf_(Gt[pb * 33 + kc]);
                float fg = sigmoidf_(Gt[pb * 33 + 8 + kc]);
                float gg = tanhf(Gt[pb * 33 + 16 + kc]);
                float og = sigmoidf_(Gt[pb * 33 + 24 + kc]);
                float cn = fg * cst[q] + ig * gg;
                cst[q] = cn;
                hb[q] = f2bf(og * tanhf(cn));
            }
            size_t off = (size_t)pb * 512 + 8 * j + pk;
            *(ushort4*)&hnxt[off] = *(ushort4*)hb;
            *(ushort4*)&h_all[(size_t)(t * B_ + pb) * 512 + 8 * j + pk] = *(ushort4*)hb;
        }
        __threadfence();     // release h writes (per-wave, before signaling)
        __syncthreads();
        if (tid == 0)
            __hip_atomic_store(&flags[j * 32], t + 1, __ATOMIC_RELEASE,
                               __HIP_MEMORY_SCOPE_AGENT);
        if (tid < 64) {
            while (__hip_atomic_load(&flags[tid * 32], __ATOMIC_ACQUIRE,
                                     __HIP_MEMORY_SCOPE_AGENT) < t + 1)
                __builtin_amdgcn_s_sleep(1);
        }
        __threadfence();     // acquire: invalidate L1 before reading new h
        __syncthreads();
    }
}

// ---------------------------------------------------------------------------
// logits GEMM, 128x128 tile, BK=32. A=h_all [2560,512], B=cWo [VOCP,512].
// f32 out + bo, col-guarded -> d_out second half.
// ---------------------------------------------------------------------------
__global__ __launch_bounds__(256) void gemm128(const u16* __restrict__ A,
                                               const u16* __restrict__ Bm,
                                               const u16* __restrict__ biasbf,
                                               float* __restrict__ C) {
    __shared__ u16 As[128 * 32];
    __shared__ u16 Bs[128 * 32];
    int tid = threadIdx.x;
    int n0 = blockIdx.x * 128, m0 = blockIdx.y * 128;
    int w = tid >> 6, lane = tid & 63;
    int wm = (w & 1) * 64, wn = (w >> 1) * 64;
    int mrow = lane & 15, quad = lane >> 4;
    float4v acc[4][4] = {};
    for (int k0 = 0; k0 < 512; k0 += 32) {
        #pragma unroll
        for (int q = 0; q < 2; q++) {
            int idx = tid * 2 + q;
            int r = idx >> 2, cc = (idx & 3) * 8;
            *(uint4*)&As[r * 32 + cc] = *(const uint4*)&A[(size_t)(m0 + r) * 512 + k0 + cc];
            *(uint4*)&Bs[r * 32 + cc] = *(const uint4*)&Bm[(size_t)(n0 + r) * 512 + k0 + cc];
        }
        __syncthreads();
        short8 af[4], bfv[4];
        #pragma unroll
        for (int i = 0; i < 4; i++)
            af[i] = *(const short8*)&As[(wm + i * 16 + mrow) * 32 + quad * 8];
        #pragma unroll
        for (int jn = 0; jn < 4; jn++)
            bfv[jn] = *(const short8*)&Bs[(wn + jn * 16 + mrow) * 32 + quad * 8];
        #pragma unroll
        for (int i = 0; i < 4; i++)
            #pragma unroll
            for (int jn = 0; jn < 4; jn++)
                acc[i][jn] = __builtin_amdgcn_mfma_f32_16x16x32_bf16(af[i], bfv[jn], acc[i][jn], 0, 0, 0);
        __syncthreads();
    }
    #pragma unroll
    for (int i = 0; i < 4; i++) {
        #pragma unroll
        for (int jn = 0; jn < 4; jn++) {
            int gcol = n0 + wn + jn * 16 + mrow;
            if (gcol >= VOC) continue;
            float bias = bf2f(biasbf[gcol]);
            #pragma unroll
            for (int r = 0; r < 4; r++) {
                int grow = m0 + wm + i * 16 + quad * 4 + r;
                C[(size_t)grow * VOC + gcol] = acc[i][jn][r] + bias;
            }
        }
    }
}

// ---------------------------------------------------------------------------
// fused log_softmax + softmax over d_out rows (f32). Raw logits in 2nd half.
// ---------------------------------------------------------------------------
__global__ __launch_bounds__(256) void softmax_out(float* __restrict__ out) {
    __shared__ float red[256];
    int r = blockIdx.x, tid = threadIdx.x;
    const size_t HALF4 = (size_t)T_ * B_ * VOC / 4;
    float4* outv = (float4*)out;
    float4* src = outv + HALF4 + (size_t)r * (VOC / 4);
    float4 lv[10];
    float m = -1e30f;
    #pragma unroll
    for (int jq = 0; jq < 10; jq++) {
        int i4 = tid + jq * 256;
        if (i4 < VOC / 4) {
            float4 v = src[i4];
            lv[jq] = v;
            m = fmaxf(m, fmaxf(fmaxf(v.x, v.y), fmaxf(v.z, v.w)));
        } else {
            lv[jq] = make_float4(-1e30f, -1e30f, -1e30f, -1e30f);
        }
    }
    red[tid] = m; __syncthreads();
    for (int s = 128; s; s >>= 1) { if (tid < s) red[tid] = fmaxf(red[tid], red[tid + s]); __syncthreads(); }
    m = red[0]; __syncthreads();
    float sum = 0.f;
    #pragma unroll
    for (int jq = 0; jq < 10; jq++)
        sum += expf(lv[jq].x - m) + expf(lv[jq].y - m) + expf(lv[jq].z - m) + expf(lv[jq].w - m);
    red[tid] = sum; __syncthreads();
    for (int s = 128; s; s >>= 1) { if (tid < s) red[tid] += red[tid + s]; __syncthreads(); }
    float logZ = m + logf(red[0]);
    float4* dls = outv + (size_t)r * (VOC / 4);
    #pragma unroll
    for (int jq = 0; jq < 10; jq++) {
        int i4 = tid + jq * 256;
        if (i4 < VOC / 4) {
            float4 v = lv[jq];
            float4 ls = make_float4(v.x - logZ, v.y - logZ, v.z - logZ, v.w - logZ);
            dls[i4] = ls;
            src[i4] = make_float4(expf(ls.x), expf(ls.y), expf(ls.z), expf(ls.w));
        }
    }
}

extern "C" void kernel_launch(void* const* d_in, const int* in_sizes, int n_in,
                              void* d_out, int out_size, void* d_ws, size_t ws_size,
                              hipStream_t stream) {
    const float* features = (const float*)d_in[0];
    const int* captions   = (const int*)d_in[1];
    const float* W_init_h = (const float*)d_in[2];
    const float* W_init_c = (const float*)d_in[3];
    const float* Wv       = (const float*)d_in[4];
    // d_in[5] bv, d_in[6] Wa, d_in[7] ba unused (softmax shift-invariance)
    const float* embed_t  = (const float*)d_in[8];
    const float* W_ih     = (const float*)d_in[9];
    const float* W_hh     = (const float*)d_in[10];
    const float* b_ih     = (const float*)d_in[11];
    const float* b_hh     = (const float*)d_in[12];
    const float* Wo       = (const float*)d_in[13];
    const float* bo       = (const float*)d_in[14];
    float* out = (float*)d_out;

    // workspace layout (~41.4 MB)
    char* base = (char*)d_ws;
    int*   flags   = (int*)(base + 0);            // 64 x 128B-padded
    u16*   fbar_bf = (u16*)(base + 8192);
    u16*   ctx_bf  = (u16*)(base + 139264);
    u16*   h_pp    = (u16*)(base + 270336);       // 2 x 128*512 bf16
    float* c_f32   = (float*)(base + 532480);
    float* gconst  = (float*)(base + 794624);     // [128,2048] f32
    u16*   Ebf     = (u16*)(base + 1843200);      // [2560,256] bf16
    float* gbase   = (float*)(base + 3153920);    // [2560,2048] f32
    u16*   h_all   = (u16*)(base + 24125440);     // [2560,512] bf16
    u16*   cWih    = (u16*)(base + 26746880);     // [2048,768] bf16
    u16*   cWhh    = (u16*)(base + 29892608);     // [2048,512]
    u16*   cWo     = (u16*)(base + 31989760);     // [VOCP,512] padded
    u16*   cWinit  = (u16*)(base + 42344448);     // [1024,512] (Winh;Winc)
    u16*   cbih    = (u16*)(base + 43393024);
    u16*   cbhh    = (u16*)(base + 43397120);
    u16*   cbo     = (u16*)(base + 43401216);     // [VOCP] padded

    // 1) weight conversion (+ flag zero)
    conv_all<<<32568, 256, 0, stream>>>(W_ih, W_hh, Wo, W_init_h, W_init_c,
                                        b_ih, b_hh, bo,
                                        cWih, cWhh, cWo, cWinit, cbih, cbhh, cbo, flags);
    // 2) fused attention + context/mean (single feature pass)
    prep2<<<B_, 256, 0, stream>>>(features, Wv, fbar_bf, ctx_bf);
    // 3) embeddings (time-major)
    gather_emb<<<T_ * B_, 256, 0, stream>>>(captions, embed_t, Ebf);
    // 4) h0 | c0 = fbar @ [Winh; Winc]^T
    gemm_bt<<<dim3(16, 2), 256, 0, stream>>>(
        fbar_bf, 512, cWinit, 512, B_, 1024, 512,
        nullptr, nullptr, nullptr, -1, c_f32, h_pp, 1024, 2);
    // 5) gconst = ctx @ W_ih[:, :512]^T + b_ih + b_hh
    gemm_bt<<<dim3(32, 2), 256, 0, stream>>>(
        ctx_bf, 512, cWih, 768, B_, 2048, 512,
        cbih, cbhh, nullptr, -1, gconst, nullptr, 2048, 1);
    // 6) gbase = E @ W_ih[:, 512:768]^T + gconst[b]
    gemm_bt<<<dim3(32, 40), 256, 0, stream>>>(
        Ebf, 256, cWih + 512, 768, T_ * B_, 2048, 256,
        nullptr, nullptr, gconst, 127, gbase, nullptr, 2048, 1);
    // 7) fused 20-step LSTM recurrence (single persistent launch)
    recurrence<<<NBLK, 256, 0, stream>>>(cWhh, gbase, c_f32, h_pp, h_all, flags);
    // 8) logits = h_all @ Wo^T + bo -> f32 raw into d_out's second half
    gemm128<<<dim3(VOCP / 128, (T_ * B_) / 128), 256, 0, stream>>>(
        h_all, cWo, cbo, out + (size_t)T_ * B_ * VOC);
    // 9) fused log_softmax + softmax in place
    softmax_out<<<T_ * B_, 256, 0, stream>>>(out);
}